// Round 7
// baseline (346.728 us; speedup 1.0000x reference)
//
#include <hip/hip_runtime.h>

typedef unsigned short u16;
typedef unsigned int u32;
typedef __attribute__((ext_vector_type(4))) float f32x4;
typedef __attribute__((ext_vector_type(8))) short short8;
typedef __attribute__((ext_vector_type(4))) short short4v;

#define BB   2
#define SQL  2048
#define SKVL 4096
#define DM   1024
#define NH   16
#define DK   64
#define L2E  1.44269504f

#if __has_builtin(__builtin_amdgcn_exp2f)
#define EXP2(x) __builtin_amdgcn_exp2f(x)
#else
#define EXP2(x) exp2f(x)
#endif

#define MFMA32(a, b, c) __builtin_amdgcn_mfma_f32_16x16x32_bf16(a, b, c, 0, 0, 0)
#define MFMA16(a, b, c) __builtin_amdgcn_mfma_f32_16x16x16bf16_1k(a, b, c, 0, 0, 0)

__device__ __forceinline__ u16 f2bf(float f) {
  union { float f; unsigned u; } v; v.f = f;
  unsigned r = v.u + 0x7fff + ((v.u >> 16) & 1);   // RNE
  return (u16)(r >> 16);
}

// pack4 via v_perm_b32: hi16 after round-half-up
__device__ __forceinline__ short4v pack4(float p0, float p1, float p2, float p3) {
  union { float f; u32 u; } a, b, c, d;
  a.f = p0; b.f = p1; c.f = p2; d.f = p3;
  union { uint2 v; short4v s; } r;
  r.v.x = __builtin_amdgcn_perm(b.u + 0x8000u, a.u + 0x8000u, 0x07060302);
  r.v.y = __builtin_amdgcn_perm(d.u + 0x8000u, c.u + 0x8000u, 0x07060302);
  return r.s;
}

// async global->LDS, 16B per lane; lds base wave-uniform, lane i -> base + i*16.
__device__ __forceinline__ void gload16(const void* g, void* lds) {
  __builtin_amdgcn_global_load_lds(
      (const __attribute__((address_space(1))) unsigned int*)g,
      (__attribute__((address_space(3))) unsigned int*)lds, 16, 0, 0);
}

// ---------------- fused preprocessing: rmsnorm | fp32->bf16 cvt | 4x weight transpose ----------------
__global__ void pre_kernel(const float* __restrict__ hidden, const float* __restrict__ lnw,
                           const float* __restrict__ kvs,
                           const float* __restrict__ Wq, const float* __restrict__ Wk,
                           const float* __restrict__ Wv, const float* __restrict__ Wo,
                           u16* __restrict__ normed, u16* __restrict__ kvb,
                           u16* __restrict__ Wqt, u16* __restrict__ Wkt,
                           u16* __restrict__ Wvt, u16* __restrict__ Wot) {
  __shared__ float red[4];
  __shared__ float tile[32][33];
  int bid = blockIdx.x, t = threadIdx.x;
  if (bid < 4096) {
    int row = bid;
    float4 v = ((const float4*)(hidden + (size_t)row * DM))[t];
    float ss = v.x * v.x + v.y * v.y + v.z * v.z + v.w * v.w;
#pragma unroll
    for (int m = 32; m >= 1; m >>= 1) ss += __shfl_xor(ss, m, 64);
    int lane = t & 63, wv = t >> 6;
    if (lane == 0) red[wv] = ss;
    __syncthreads();
    float total = red[0] + red[1] + red[2] + red[3];
    float scale = rsqrtf(total * (1.0f / DM) + 1e-6f);
    float4 g = ((const float4*)lnw)[t];
    ushort4 o;
    o.x = f2bf(v.x * scale * g.x);
    o.y = f2bf(v.y * scale * g.y);
    o.z = f2bf(v.z * scale * g.z);
    o.w = f2bf(v.w * scale * g.w);
    ((ushort4*)(normed + (size_t)row * DM))[t] = o;
  } else if (bid < 12288) {
    int i = (bid - 4096) * 256 + t;
    float4 v = ((const float4*)kvs)[i];
    ushort4 o;
    o.x = f2bf(v.x); o.y = f2bf(v.y); o.z = f2bf(v.z); o.w = f2bf(v.w);
    ((ushort4*)kvb)[i] = o;
  } else {
    int g = bid - 12288;
    int z = g >> 10;
    const float* W = (z == 0) ? Wq : (z == 1) ? Wk : (z == 2) ? Wv : Wo;
    u16* Wt = (z == 0) ? Wqt : (z == 1) ? Wkt : (z == 2) ? Wvt : Wot;
    int xx = g & 31, yy = (g >> 5) & 31;
    int tx = t & 31, ty = t >> 5;
    int k0 = yy * 32, n0 = xx * 32;
#pragma unroll
    for (int i = 0; i < 4; i++)
      tile[ty + i * 8][tx] = W[(size_t)(k0 + ty + i * 8) * DM + n0 + tx];
    __syncthreads();
#pragma unroll
    for (int i = 0; i < 4; i++)
      Wt[(size_t)(n0 + ty + i * 8) * DM + k0 + tx] = f2bf(tile[tx][ty + i * 8]);
  }
}

// ---------------- merged Q/K/V projection, 1280 blocks, BK=64, XCD-swizzled ----------------
// Swizzle assumes round-robin block->XCD (bid % 8): the 8 blocks sharing the
// large re-read panel get bids congruent mod 8 -> same XCD -> panel served from L2.
__global__ void proj_kernel(const u16* __restrict__ normed, const u16* __restrict__ kvb,
                            const u16* __restrict__ Wqt, const u16* __restrict__ Wkt,
                            const u16* __restrict__ Wvt,
                            u16* __restrict__ Qb, u16* __restrict__ Kbf,
                            u16* __restrict__ Vtb) {
  const int K = 1024;
  __shared__ __align__(16) u16 Al[128 * 64];   // [half2][128][32]
  __shared__ __align__(16) u16 Bl[128 * 64];
  int tid = threadIdx.x, lane = tid & 63, w = tid >> 6;
  int l15 = lane & 15, quad = lane >> 4;
  int wy = w >> 1, wx = w & 1;

  int bid = blockIdx.x;
  int mode;
  const u16 *A, *Bt;
  int tm, tn;
  if (bid < 256) {          // Q: 32 tm x 8 tn; A-panel (normed) shared per-XCD
    mode = 0; A = normed; Bt = Wqt;
    int xcd = bid & 7, j = bid >> 3;
    tm = ((j >> 3) * 8 + xcd) * 128; tn = (j & 7) * 128;
  } else if (bid < 768) {   // K: 64 tm x 8 tn; A-panel (kvb) shared per-XCD
    mode = 1; A = kvb; Bt = Wkt;
    int kid = bid - 256;
    int xcd = kid & 7, j = kid >> 3;
    tm = ((j >> 3) * 8 + xcd) * 128; tn = (j & 7) * 128;
  } else {                  // V: 8 tm x 64 tn; B-panel (kvb) shared per-XCD
    mode = 2; A = Wvt; Bt = kvb;
    int vid = bid - 768;
    int xcd = vid & 7, j = vid >> 3;
    tn = ((j >> 3) * 8 + xcd) * 128; tm = (j & 7) * 128;
  }

  f32x4 acc[4][4] = {};
  for (int k0 = 0; k0 < K; k0 += 64) {
    __syncthreads();
#pragma unroll
    for (int r = 0; r < 2; r++) {
      int mg = w * 2 + r;
      const u16* ar = A + (size_t)(tm + mg * 16 + l15) * K + k0 + quad * 8;
      const u16* br = Bt + (size_t)(tn + mg * 16 + l15) * K + k0 + quad * 8;
      gload16(ar, &Al[mg * 512]);
      gload16(ar + 32, &Al[4096 + mg * 512]);
      gload16(br, &Bl[mg * 512]);
      gload16(br + 32, &Bl[4096 + mg * 512]);
    }
    __syncthreads();
#pragma unroll
    for (int c = 0; c < 2; c++) {
      short8 af[4], bfr[4];
#pragma unroll
      for (int i = 0; i < 4; i++) {
        af[i] = *(const short8*)&Al[c * 4096 + ((wy * 4 + i) * 64 + lane) * 8];
        bfr[i] = *(const short8*)&Bl[c * 4096 + ((wx * 4 + i) * 64 + lane) * 8];
      }
#pragma unroll
      for (int mt = 0; mt < 4; mt++)
#pragma unroll
        for (int nt = 0; nt < 4; nt++)
          acc[mt][nt] = MFMA32(af[mt], bfr[nt], acc[mt][nt]);
    }
  }

#pragma unroll
  for (int mt = 0; mt < 4; mt++) {
    int m0 = tm + wy * 64 + mt * 16 + quad * 4;
#pragma unroll
    for (int nt = 0; nt < 4; nt++) {
      int n = tn + wx * 64 + nt * 16 + l15;
      if (mode == 0) {
#pragma unroll
        for (int r = 0; r < 4; r++)
          Qb[(size_t)(m0 + r) * 1024 + n] = f2bf(acc[mt][nt][r] * L2E);
      } else if (mode == 1) {
#pragma unroll
        for (int r = 0; r < 4; r++)
          Kbf[(size_t)(m0 + r) * 1024 + n] = f2bf(acc[mt][nt][r]);
      } else {
        int b = n >> 12, skv = n & 4095;
        int kvt = skv >> 6, kvl = skv & 63;
        int p = kvl >> 5, kth = (kvl >> 4) & 1, qd = (kvl >> 2) & 3, elo = kvl & 3;
        int e = kth * 4 + elo;
        int h = m0 >> 6, d0 = m0 & 63;
        size_t base = ((size_t)((b * NH + h) * 64 + kvt) << 12) + (size_t)(p * 4 + qd) * 512 + e;
#pragma unroll
        for (int r = 0; r < 4; r++)
          Vtb[base + (size_t)(d0 + r) * 8] = f2bf(acc[mt][nt][r]);
      }
    }
  }
}

// ---------------- flash attention: mask as MFMA C-init, l via MFMA, reg P ----------------
__global__ __launch_bounds__(256, 2) void flash_kernel(
    const u16* __restrict__ Qp, const u16* __restrict__ Kp, const u16* __restrict__ Vtb,
    const float* __restrict__ mask, u16* __restrict__ ctx) {
  __shared__ __align__(16) char smem[65536];
  u16* Kbuf = (u16*)smem;                 // [buf2][grp2][4096]
  u16* Vbuf = (u16*)(smem + 32768);       // [buf2][grp2][4096]
  float* Ox = (float*)smem;               // merge reuse: [128][64]
  float* Ll = (float*)(smem + 32768);     // merge reuse: [128]

  int tid = threadIdx.x, lane = tid & 63, w = tid >> 6;
  int l15 = lane & 15, quad = lane >> 4;
  int grp = w >> 1, wg = w & 1;
  int qb = blockIdx.x, bh = blockIdx.y;
  int b = bh >> 4, h = bh & 15;
  int q0 = qb * 128 + wg * 64;

  short8 qf[4][2];
#pragma unroll
  for (int mt = 0; mt < 4; mt++)
#pragma unroll
    for (int kf = 0; kf < 2; kf++)
      qf[mt][kf] = *(const short8*)(Qp + (size_t)(b * SQL + q0 + mt * 16 + l15) * DM +
                                    h * DK + kf * 32 + quad * 8);

  f32x4 of[4][4] = {};
  f32x4 la[4] = {};
  const short4v ones = {0x3F80, 0x3F80, 0x3F80, 0x3F80};  // bf16 1.0

  const size_t vblob = (size_t)(b * NH + h) * 64 * 4096;
  const float* mrow = mask + (size_t)b * SKVL;

  auto stage = [&](int tileIdx, int buf) {
    int kv0 = tileIdx * 64;
    u16* Kd = Kbuf + (buf * 2 + grp) * 4096;
    u16* Vd = Vbuf + (buf * 2 + grp) * 4096;
#pragma unroll
    for (int r = 0; r < 4; r++) {
      int u = wg * 4 + r;
      int kt = u >> 1, kf = u & 1;
      gload16(Kp + (size_t)(b * SKVL + kv0 + kt * 16 + l15) * DM + h * DK + kf * 32 + quad * 8,
              &Kd[u * 512]);
      gload16(Vtb + vblob + (size_t)tileIdx * 4096 + u * 512 + lane * 8, &Vd[u * 512]);
    }
  };

  f32x4 mlc[4], mln[4];
  {
    int kv0 = grp * 64;
#pragma unroll
    for (int kt = 0; kt < 4; kt++)
      mlc[kt] = *(const f32x4*)(mrow + kv0 + kt * 16 + quad * 4) * L2E;
  }
  stage(grp, 0);

  for (int it = 0; it < 32; ++it) {
    __syncthreads();
    if (it + 1 < 32) {
      stage((it + 1) * 2 + grp, (it + 1) & 1);
      int kvn = ((it + 1) * 2 + grp) * 64;
#pragma unroll
      for (int kt = 0; kt < 4; kt++)
        mln[kt] = *(const f32x4*)(mrow + kvn + kt * 16 + quad * 4) * L2E;
    }
    const u16* Kg = Kbuf + ((it & 1) * 2 + grp) * 4096;
    const u16* Vg = Vbuf + ((it & 1) * 2 + grp) * 4096;

#pragma unroll
    for (int ktp = 0; ktp < 2; ktp++) {
      short4v pa[2][4];
#pragma unroll
      for (int kth = 0; kth < 2; kth++) {
        int kt = ktp * 2 + kth;
        short8 k0 = *(const short8*)&Kg[((kt * 2 + 0) * 64 + lane) * 8];
        short8 k1 = *(const short8*)&Kg[((kt * 2 + 1) * 64 + lane) * 8];
#pragma unroll
        for (int mt = 0; mt < 4; mt++) {
          f32x4 st = mlc[kt];             // mask*log2e as accumulator init
          st = MFMA32(k0, qf[mt][0], st);
          st = MFMA32(k1, qf[mt][1], st);
          pa[kth][mt] = pack4(EXP2(st[0]), EXP2(st[1]), EXP2(st[2]), EXP2(st[3]));
        }
      }
#pragma unroll
      for (int mt = 0; mt < 4; mt++) {    // l rowsum via matrix pipe
        la[mt] = MFMA16(pa[0][mt], ones, la[mt]);
        la[mt] = MFMA16(pa[1][mt], ones, la[mt]);
      }
#pragma unroll
      for (int nt = 0; nt < 4; nt++) {
        short8 vv = *(const short8*)&Vg[((ktp * 4 + quad) * 64 + nt * 16 + l15) * 8];
        short4v vlo = {vv[0], vv[1], vv[2], vv[3]};
        short4v vhi = {vv[4], vv[5], vv[6], vv[7]};
#pragma unroll
        for (int mt = 0; mt < 4; mt++) {
          of[mt][nt] = MFMA16(pa[0][mt], vlo, of[mt][nt]);
          of[mt][nt] = MFMA16(pa[1][mt], vhi, of[mt][nt]);
        }
      }
    }
#pragma unroll
    for (int kt = 0; kt < 4; kt++) mlc[kt] = mln[kt];
  }

  __syncthreads();
  if (grp == 1) {
#pragma unroll
    for (int mt = 0; mt < 4; mt++) {
#pragma unroll
      for (int nt = 0; nt < 4; nt++)
#pragma unroll
        for (int r = 0; r < 4; r++)
          Ox[(wg * 64 + mt * 16 + quad * 4 + r) * 64 + nt * 16 + l15] = of[mt][nt][r];
      if (l15 == 0)
#pragma unroll
        for (int r = 0; r < 4; r++) Ll[wg * 64 + mt * 16 + quad * 4 + r] = la[mt][r];
    }
  }
  __syncthreads();
  if (grp == 0) {
#pragma unroll
    for (int mt = 0; mt < 4; mt++)
#pragma unroll
      for (int r = 0; r < 4; r++) {
        int ql = wg * 64 + mt * 16 + quad * 4 + r;
        float inv = 1.0f / (la[mt][r] + Ll[ql]);
        int q = qb * 128 + ql;
#pragma unroll
        for (int nt = 0; nt < 4; nt++) {
          float ov = of[mt][nt][r] + Ox[ql * 64 + nt * 16 + l15];
          ctx[(size_t)(b * SQL + q) * DM + h * DK + nt * 16 + l15] = f2bf(ov * inv);
        }
      }
  }
}

// ---------------- O projection + residual, BK=64, XCD-swizzled (32 tm x 8 tn) ----------------
__global__ void ogemm_kernel(const u16* __restrict__ A, const u16* __restrict__ Bt,
                             float* __restrict__ C, const float* __restrict__ resid) {
  const int K = 1024;
  __shared__ __align__(16) u16 Al[128 * 64];
  __shared__ __align__(16) u16 Bl[128 * 64];
  int tid = threadIdx.x, lane = tid & 63, w = tid >> 6;
  int l15 = lane & 15, quad = lane >> 4;
  int wy = w >> 1, wx = w & 1;
  int bid = blockIdx.x;
  int xcd = bid & 7, j = bid >> 3;
  int tm = ((j >> 3) * 8 + xcd) * 128, tn = (j & 7) * 128;
  f32x4 acc[4][4] = {};

  for (int k0 = 0; k0 < K; k0 += 64) {
    __syncthreads();
#pragma unroll
    for (int r = 0; r < 2; r++) {
      int mg = w * 2 + r;
      const u16* ar = A + (size_t)(tm + mg * 16 + l15) * K + k0 + quad * 8;
      const u16* br = Bt + (size_t)(tn + mg * 16 + l15) * K + k0 + quad * 8;
      gload16(ar, &Al[mg * 512]);
      gload16(ar + 32, &Al[4096 + mg * 512]);
      gload16(br, &Bl[mg * 512]);
      gload16(br + 32, &Bl[4096 + mg * 512]);
    }
    __syncthreads();
#pragma unroll
    for (int c = 0; c < 2; c++) {
      short8 af[4], bfr[4];
#pragma unroll
      for (int i = 0; i < 4; i++) {
        af[i] = *(const short8*)&Al[c * 4096 + ((wy * 4 + i) * 64 + lane) * 8];
        bfr[i] = *(const short8*)&Bl[c * 4096 + ((wx * 4 + i) * 64 + lane) * 8];
      }
#pragma unroll
      for (int mt = 0; mt < 4; mt++)
#pragma unroll
        for (int nt = 0; nt < 4; nt++)
          acc[mt][nt] = MFMA32(af[mt], bfr[nt], acc[mt][nt]);
    }
  }

#pragma unroll
  for (int mt = 0; mt < 4; mt++) {
    int m0 = tm + wy * 64 + mt * 16 + quad * 4;
#pragma unroll
    for (int nt = 0; nt < 4; nt++) {
      int n = tn + wx * 64 + nt * 16 + l15;
#pragma unroll
      for (int r = 0; r < 4; r++) {
        size_t idx = (size_t)(m0 + r) * 1024 + n;
        C[idx] = resid[idx] + acc[mt][nt][r];
      }
    }
  }
}

extern "C" void kernel_launch(void* const* d_in, const int* in_sizes, int n_in,
                              void* d_out, int out_size, void* d_ws, size_t ws_size,
                              hipStream_t stream) {
  const float* hidden = (const float*)d_in[0];
  const float* kvs    = (const float*)d_in[1];
  const float* mask   = (const float*)d_in[2];
  const float* lnw    = (const float*)d_in[3];
  const float* Wq     = (const float*)d_in[4];
  const float* Wk     = (const float*)d_in[5];
  const float* Wv     = (const float*)d_in[6];
  const float* Wo     = (const float*)d_in[7];
  char* ws = (char*)d_ws;

  u16* normed = (u16*)(ws + 0);           // 8 MB
  u16* kvb    = (u16*)(ws + 8388608);     // 16 MB
  u16* Wqt    = (u16*)(ws + 25165824);    // 2 MB
  u16* Wkt    = (u16*)(ws + 27262976);    // 2 MB
  u16* Wvt    = (u16*)(ws + 29360128);    // 2 MB
  u16* Wot    = (u16*)(ws + 31457280);    // 2 MB
  u16* Qb     = (u16*)(ws + 33554432);    // 8 MB (pre-scaled by log2e)
  u16* Kbf    = (u16*)(ws + 41943040);    // 16 MB
  u16* Vtb    = (u16*)(ws + 58720256);    // 16 MB (blob layout)
  u16* ctxb   = (u16*)(ws + 75497472);    // 8 MB

  pre_kernel<<<16384, 256, 0, stream>>>(hidden, lnw, kvs, Wq, Wk, Wv, Wo,
                                        normed, kvb, Wqt, Wkt, Wvt, Wot);
  proj_kernel<<<1280, 256, 0, stream>>>(normed, kvb, Wqt, Wkt, Wvt, Qb, Kbf, Vtb);
  flash_kernel<<<dim3(SQL / 128, BB * NH), 256, 0, stream>>>(Qb, Kbf, Vtb, mask, ctxb);
  ogemm_kernel<<<256, 256, 0, stream>>>(ctxb, Wot, (float*)d_out, hidden);
}